// Round 1
// baseline (587.245 us; speedup 1.0000x reference)
//
#include <hip/hip_runtime.h>
#include <math.h>

#define B 4
#define NPTS 300000
#define G 15
#define G3 3375
#define PAIR_FLOATS (4*G3)       // 13500 floats: one (b,set) grid, 4 channels
#define SCENE_FLOATS (B*12*G3)   // 162000
#define KMAX 42                  // replicas per (b,set) pair -> 12*42 = 504 blocks

__device__ __forceinline__ float eluf(float v) {
    return v > 0.0f ? v : __expf(v) - 1.0f;
}

// ---------------------------------------------------------------------------
// Stage 1: per-point features -> MLP -> scatter-max into a PRIVATE LDS grid
// (54 KB = full 4ch x 15^3 grid for this block's (b,set) pair), then flush
// with plain coalesced stores into a per-block replica. NO global atomics.
// grid: (K, B, 3); block 256. 2 blocks/CU (LDS-limited).
// ---------------------------------------------------------------------------
__global__ __launch_bounds__(256)
void point_kernel(const float* __restrict__ P0,   // inputs  (set 0)
                  const float* __restrict__ P1,   // goals   (set 1)
                  const float* __restrict__ P2,   // backgrounds (set 2)
                  const float* __restrict__ W1, const float* __restrict__ b1,
                  const float* __restrict__ W2, const float* __restrict__ b2,
                  const float* __restrict__ W3, const float* __restrict__ b3,
                  float* __restrict__ scenesR, int K)
{
    __shared__ unsigned sg[PAIR_FLOATS];   // 54000 B; uint-ordered positive floats

    int b   = blockIdx.y;
    int set = blockIdx.z;
    int rep = blockIdx.x;
    int pair = b * 3 + set;
    const float* P = (set == 0) ? P0 : ((set == 1) ? P1 : P2);

    for (int i = threadIdx.x; i < PAIR_FLOATS; i += 256) sg[i] = 0u;
    __syncthreads();

    int chunk = (NPTS + K - 1) / K;
    int start = rep * chunk;
    int end   = min(NPTS, start + chunk);

    for (int idx = start + (int)threadIdx.x; idx < end; idx += 256) {
        const float* p = P + ((size_t)b * NPTS + idx) * 3;
        float px = p[0], py = p[1], pz = p[2];

        const float HI = 14.9999f;  // GZ - 1e-4
        float cx = floorf(fminf(fmaxf(px, 0.0f), HI));
        float cy = floorf(fminf(fmaxf(py, 0.0f), HI));
        float cz = floorf(fminf(fmaxf(pz, 0.0f), HI));

        float x[12];
        x[0] = px - (cx + 0.5f); x[1] = py - (cy + 0.5f); x[2] = pz - (cz + 0.5f);
        x[3] = px - cx;          x[4] = py - cy;          x[5] = pz - cz;
        x[6] = px - (cx + 1.0f); x[7] = py - (cy + 1.0f); x[8] = pz - (cz + 1.0f);
        x[9]  = sqrtf(x[0]*x[0] + x[1]*x[1] + x[2]*x[2]);
        x[10] = sqrtf(x[3]*x[3] + x[4]*x[4] + x[5]*x[5]);
        x[11] = sqrtf(x[6]*x[6] + x[7]*x[7] + x[8]*x[8]);

        // weights are wave-uniform -> s_load into SGPRs, FMA takes SGPR operand
        float h1[16];
#pragma unroll
        for (int j = 0; j < 16; ++j) {
            float s = b1[j];
#pragma unroll
            for (int k = 0; k < 12; ++k) s = fmaf(x[k], W1[k*16 + j], s);
            h1[j] = eluf(s);
        }
        float h2[16];
#pragma unroll
        for (int j = 0; j < 16; ++j) {
            float s = b2[j];
#pragma unroll
            for (int k = 0; k < 16; ++k) s = fmaf(h1[k], W2[k*16 + j], s);
            h2[j] = eluf(s);
        }
        float o[4];
#pragma unroll
        for (int j = 0; j < 4; ++j) {
            float s = b3[j];
#pragma unroll
            for (int k = 0; k < 16; ++k) s = fmaf(h2[k], W3[k*4 + j], s);
            o[j] = s;
        }

        int cell = (((int)cx) * G + (int)cy) * G + (int)cz;
#pragma unroll
        for (int c = 0; c < 4; ++c) {
            float v = o[c];
            if (v > 0.0f)   // grid floor is 0; positive floats order like uints
                atomicMax(&sg[c * G3 + cell], __float_as_uint(v));
        }
    }
    __syncthreads();

    float* dst = scenesR + ((size_t)pair * K + rep) * PAIR_FLOATS;
    for (int i = threadIdx.x; i < PAIR_FLOATS; i += 256)
        dst[i] = __uint_as_float(sg[i]);
}

// ---------------------------------------------------------------------------
// max-reduce K replicas per pair -> scenes [B,12,G3] (== [pair][13500] linear)
// ---------------------------------------------------------------------------
__global__ __launch_bounds__(256)
void reduce_kernel(const float* __restrict__ scenesR, float* __restrict__ scenes,
                   int K)
{
    int t = blockIdx.x * 256 + threadIdx.x;
    if (t >= SCENE_FLOATS) return;
    int pair = t / PAIR_FLOATS;
    int j    = t - pair * PAIR_FLOATS;
    const float* src = scenesR + (size_t)pair * K * PAIR_FLOATS + j;
    float m = 0.0f;
    for (int r = 0; r < K; ++r)
        m = fmaxf(m, src[(size_t)r * PAIR_FLOATS]);
    scenes[t] = m;
}

// ---------------------------------------------------------------------------
// conv1: scenes [B,12,15,15,15] -> y0 [B,8,8,8,8] (raw conv+bias) + stats0
// grid: (b,co,od)=256 blocks; threads 256 = (ciq,oh,ow); ciq handles 3 ci
// ---------------------------------------------------------------------------
__global__ __launch_bounds__(256)
void conv1_kernel(const float* __restrict__ scenes,
                  const float* __restrict__ w,    // [8,12,125]
                  const float* __restrict__ bias, // [8]
                  float* __restrict__ y, float* __restrict__ stats)
{
    __shared__ float sred[256];
    int bx = blockIdx.x;
    int od = bx & 7, co = (bx >> 3) & 7, b = bx >> 6;
    int tid = threadIdx.x;
    int ow = tid & 7, oh = (tid >> 3) & 7, ciq = tid >> 6;

    float s = 0.0f;
    for (int cin = 0; cin < 3; ++cin) {
        int ci = ciq * 3 + cin;
        const float* sc = scenes + (size_t)(b * 12 + ci) * G3;
        const float* wc = w + (size_t)(co * 12 + ci) * 125;
#pragma unroll
        for (int kd = 0; kd < 5; ++kd) {
            int id = od * 2 - 2 + kd;
            if ((unsigned)id >= (unsigned)G) continue;   // block-uniform
#pragma unroll
            for (int kh = 0; kh < 5; ++kh) {
                int ih = oh * 2 - 2 + kh;
                bool hok = (unsigned)ih < (unsigned)G;
#pragma unroll
                for (int kw = 0; kw < 5; ++kw) {
                    int iw = ow * 2 - 2 + kw;
                    if (hok && (unsigned)iw < (unsigned)G)
                        s = fmaf(sc[(id * G + ih) * G + iw], wc[kd*25 + kh*5 + kw], s);
                }
            }
        }
    }
    sred[tid] = s;
    __syncthreads();
    if (tid < 64) {
        float tot = sred[tid] + sred[64+tid] + sred[128+tid] + sred[192+tid] + bias[co];
        y[(size_t)(b * 8 + co) * 512 + od * 64 + tid] = tot;
        float sum = tot, sq = tot * tot;
#pragma unroll
        for (int o = 32; o > 0; o >>= 1) {
            sum += __shfl_down(sum, o, 64);
            sq  += __shfl_down(sq,  o, 64);
        }
        if (tid == 0) { atomicAdd(&stats[co], sum); atomicAdd(&stats[8 + co], sq); }
    }
}

// ---------------------------------------------------------------------------
// conv_s: BN(stats_in,g,beta)+ELU applied to yin on the fly, then 5^3 conv
// grid: (b,co,od)=256 blocks; 256 threads = (ciq,oh,ow); ciq handles 2 ci
// ---------------------------------------------------------------------------
__global__ __launch_bounds__(256)
void conv_s_kernel(const float* __restrict__ yin,
                   const float* __restrict__ w,     // [8,8,125] this layer
                   const float* __restrict__ bias,  // [8]
                   const float* __restrict__ g, const float* __restrict__ bet,
                   const float* __restrict__ stats_in,
                   float* __restrict__ yout, float* __restrict__ stats_out)
{
    __shared__ float slab[8 * 5 * 144];   // [ci][kd][12][12], zero-padded
    __shared__ float sscale[8], sshift[8];
    __shared__ float sred[256];

    int bx = blockIdx.x;
    int od = bx & 7, co = (bx >> 3) & 7, b = bx >> 6;
    int tid = threadIdx.x;

    if (tid < 8) {
        float S = stats_in[tid], Q = stats_in[8 + tid];
        float m  = S * (1.0f / 2048.0f);
        float vv = Q * (1.0f / 2048.0f) - m * m;
        float rs = rsqrtf(vv + 1e-5f);
        float sc = g[tid] * rs;
        sscale[tid] = sc;
        sshift[tid] = bet[tid] - m * sc;
    }
    __syncthreads();

    for (int s = tid; s < 5760; s += 256) {
        int ci = s / 720; int r = s % 720;
        int kd = r / 144; int r2 = r % 144;
        int ph = r2 / 12, pw = r2 % 12;
        int id = od - 2 + kd, ih = ph - 2, iw = pw - 2;
        float v = 0.0f;
        if ((unsigned)id < 8u && (unsigned)ih < 8u && (unsigned)iw < 8u) {
            float raw = yin[(size_t)(b * 8 + ci) * 512 + id * 64 + ih * 8 + iw];
            float t = fmaf(raw, sscale[ci], sshift[ci]);
            v = t > 0.0f ? t : __expf(t) - 1.0f;
        }
        slab[s] = v;
    }
    __syncthreads();

    int ow = tid & 7, oh = (tid >> 3) & 7, ciq = tid >> 6;
    float s = 0.0f;
#pragma unroll
    for (int c2 = 0; c2 < 2; ++c2) {
        int ci = ciq * 2 + c2;
        const float* sl = slab + ci * 720;
        const float* wc = w + (size_t)(co * 8 + ci) * 125;
#pragma unroll
        for (int kd = 0; kd < 5; ++kd) {
#pragma unroll
            for (int kh = 0; kh < 5; ++kh) {
                const float* row = sl + kd * 144 + (oh + kh) * 12 + ow;
                const float* wr = wc + kd * 25 + kh * 5;
#pragma unroll
                for (int kw = 0; kw < 5; ++kw) s = fmaf(row[kw], wr[kw], s);
            }
        }
    }
    sred[tid] = s;
    __syncthreads();
    if (tid < 64) {
        float tot = sred[tid] + sred[64+tid] + sred[128+tid] + sred[192+tid] + bias[co];
        yout[(size_t)(b * 8 + co) * 512 + od * 64 + tid] = tot;
        float sum = tot, sq = tot * tot;
#pragma unroll
        for (int o = 32; o > 0; o >>= 1) {
            sum += __shfl_down(sum, o, 64);
            sq  += __shfl_down(sq,  o, 64);
        }
        if (tid == 0) { atomicAdd(&stats_out[co], sum); atomicAdd(&stats_out[8 + co], sq); }
    }
}

// ---------------------------------------------------------------------------
// final BN + ELU -> d_out
// ---------------------------------------------------------------------------
__global__ __launch_bounds__(256)
void bn_final_kernel(const float* __restrict__ yin,
                     const float* __restrict__ g, const float* __restrict__ bet,
                     const float* __restrict__ stats_in, float* __restrict__ outp)
{
    int i = blockIdx.x * 256 + threadIdx.x;   // 16384 total
    int c = (i >> 9) & 7;
    float S = stats_in[c], Q = stats_in[8 + c];
    float m  = S * (1.0f / 2048.0f);
    float vv = Q * (1.0f / 2048.0f) - m * m;
    float rs = rsqrtf(vv + 1e-5f);
    float sc = g[c] * rs;
    float sh = bet[c] - m * sc;
    float t = fmaf(yin[i], sc, sh);
    outp[i] = t > 0.0f ? t : __expf(t) - 1.0f;
}

// ---------------------------------------------------------------------------
extern "C" void kernel_launch(void* const* d_in, const int* in_sizes, int n_in,
                              void* d_out, int out_size, void* d_ws, size_t ws_size,
                              hipStream_t stream)
{
    const float* goals       = (const float*)d_in[0];
    const float* inputs      = (const float*)d_in[1];
    const float* backgrounds = (const float*)d_in[2];
    const float* W1 = (const float*)d_in[3];
    const float* b1 = (const float*)d_in[4];
    const float* W2 = (const float*)d_in[5];
    const float* b2 = (const float*)d_in[6];
    const float* W3 = (const float*)d_in[7];
    const float* b3 = (const float*)d_in[8];
    const float* conv1_w = (const float*)d_in[9];
    const float* conv1_b = (const float*)d_in[10];
    const float* bn1_g   = (const float*)d_in[11];
    const float* bn1_b   = (const float*)d_in[12];
    const float* convs_w = (const float*)d_in[13];
    const float* convs_b = (const float*)d_in[14];
    const float* bns_g   = (const float*)d_in[15];
    const float* bns_b   = (const float*)d_in[16];

    // replicas per (b,set) pair, sized to the workspace.
    // need: K*12*13500 + 162000 + 2*16384 + 112 floats.
    long ws_floats = (long)(ws_size / 4);
    long avail = ws_floats - (SCENE_FLOATS + 2 * 16384 + 112);
    int K = (int)(avail / (12L * PAIR_FLOATS));
    if (K > KMAX) K = KMAX;
    if (K < 1)    K = 1;

    float* wsp     = (float*)d_ws;
    float* scenesR = wsp;                                   // K * 12 * 13500
    float* scenes  = scenesR + (size_t)K * SCENE_FLOATS;    // 162000
    float* yA      = scenes + SCENE_FLOATS;                 // 16384
    float* yB      = yA + 16384;                            // 16384
    float* stats   = yB + 16384;                            // 7*16 floats

    // no scenesR memset needed: every replica float is fully written by its block
    hipMemsetAsync(stats, 0, 7 * 16 * sizeof(float), stream);

    dim3 pgrid(K, B, 3);
    point_kernel<<<pgrid, 256, 0, stream>>>(inputs, goals, backgrounds,
                                            W1, b1, W2, b2, W3, b3, scenesR, K);

    reduce_kernel<<<(SCENE_FLOATS + 255) / 256, 256, 0, stream>>>(scenesR, scenes, K);

    conv1_kernel<<<256, 256, 0, stream>>>(scenes, conv1_w, conv1_b, yA, stats);

    const float* cur = yA;
    float* nxt = yB;
    for (int i = 0; i < 6; ++i) {
        const float* g   = (i == 0) ? bn1_g : (bns_g + (i - 1) * 8);
        const float* bet = (i == 0) ? bn1_b : (bns_b + (i - 1) * 8);
        conv_s_kernel<<<256, 256, 0, stream>>>(
            cur, convs_w + (size_t)i * 8000, convs_b + i * 8,
            g, bet, stats + i * 16, nxt, stats + (i + 1) * 16);
        const float* tmp = cur; cur = nxt; nxt = (float*)tmp;
    }

    bn_final_kernel<<<64, 256, 0, stream>>>(cur, bns_g + 5 * 8, bns_b + 5 * 8,
                                            stats + 6 * 16, (float*)d_out);
}

// Round 2
// 327.406 us; speedup vs baseline: 1.7936x; 1.7936x over previous
//
#include <hip/hip_runtime.h>
#include <math.h>

#define B 4
#define NPTS 300000
#define G 15
#define G3 3375
#define PAIR_FLOATS (4*G3)       // 13500 floats: one (b,set) grid, 4 channels
#define SCENE_FLOATS (B*12*G3)   // 162000

__device__ __forceinline__ float eluf(float v) {
    return v > 0.0f ? v : __expf(v) - 1.0f;
}

// ---------------------------------------------------------------------------
// Phase A: pure MLP. One point per thread, NO loop, NO atomics, NO LDS.
// This is the structure that benched fast in the original kernel (weights
// consumed straight from the scalar cache). Streams o[4] + cell to workspace.
// grid: (ceil(m/256), B, 3)
// ---------------------------------------------------------------------------
__global__ __launch_bounds__(256)
void mlp_kernel(const float* __restrict__ P0,   // inputs  (set 0)
                const float* __restrict__ P1,   // goals   (set 1)
                const float* __restrict__ P2,   // backgrounds (set 2)
                const float* __restrict__ W1, const float* __restrict__ b1,
                const float* __restrict__ W2, const float* __restrict__ b2,
                const float* __restrict__ W3, const float* __restrict__ b3,
                float4* __restrict__ vals, int* __restrict__ cells,
                int s0, int m)
{
    int b   = blockIdx.y;
    int set = blockIdx.z;
    int i   = blockIdx.x * 256 + threadIdx.x;
    if (i >= m) return;
    const float* P = (set == 0) ? P0 : ((set == 1) ? P1 : P2);

    const float* p = P + ((size_t)b * NPTS + (size_t)(s0 + i)) * 3;
    float px = p[0], py = p[1], pz = p[2];

    const float HI = 14.9999f;  // GZ - 1e-4
    float cx = floorf(fminf(fmaxf(px, 0.0f), HI));
    float cy = floorf(fminf(fmaxf(py, 0.0f), HI));
    float cz = floorf(fminf(fmaxf(pz, 0.0f), HI));

    float x[12];
    x[0] = px - (cx + 0.5f); x[1] = py - (cy + 0.5f); x[2] = pz - (cz + 0.5f);
    x[3] = px - cx;          x[4] = py - cy;          x[5] = pz - cz;
    x[6] = px - (cx + 1.0f); x[7] = py - (cy + 1.0f); x[8] = pz - (cz + 1.0f);
    x[9]  = sqrtf(x[0]*x[0] + x[1]*x[1] + x[2]*x[2]);
    x[10] = sqrtf(x[3]*x[3] + x[4]*x[4] + x[5]*x[5]);
    x[11] = sqrtf(x[6]*x[6] + x[7]*x[7] + x[8]*x[8]);

    float h1[16];
#pragma unroll
    for (int j = 0; j < 16; ++j) {
        float s = b1[j];
#pragma unroll
        for (int k = 0; k < 12; ++k) s = fmaf(x[k], W1[k*16 + j], s);
        h1[j] = eluf(s);
    }
    float h2[16];
#pragma unroll
    for (int j = 0; j < 16; ++j) {
        float s = b2[j];
#pragma unroll
        for (int k = 0; k < 16; ++k) s = fmaf(h1[k], W2[k*16 + j], s);
        h2[j] = eluf(s);
    }
    float o[4];
#pragma unroll
    for (int j = 0; j < 4; ++j) {
        float s = b3[j];
#pragma unroll
        for (int k = 0; k < 16; ++k) s = fmaf(h2[k], W3[k*4 + j], s);
        o[j] = s;
    }

    int cell = (((int)cx) * G + (int)cy) * G + (int)cz;
    int pair = b * 3 + set;
    vals [(size_t)pair * m + i] = make_float4(o[0], o[1], o[2], o[3]);
    cells[(size_t)pair * m + i] = cell;
}

// ---------------------------------------------------------------------------
// Phase B: scatter-max into a PRIVATE LDS grid (54 KB), flush with plain
// stores into this block's replica. Tiny loop body -> nothing to hoist.
// For segment > 0, re-load own replica (stream-ordered, coherent across
// launches) and continue maxing into it.
// grid: (K, B, 3); block 256.
// ---------------------------------------------------------------------------
__global__ __launch_bounds__(256)
void scatter_kernel(const float4* __restrict__ vals,
                    const int* __restrict__ cells,
                    float* __restrict__ scenesR, int K, int m, int carry)
{
    __shared__ unsigned sg[PAIR_FLOATS];   // uint-ordered positive floats

    int rep = blockIdx.x;
    int b   = blockIdx.y;
    int set = blockIdx.z;
    int pair = b * 3 + set;
    float* myrep = scenesR + ((size_t)pair * K + rep) * PAIR_FLOATS;

    if (carry) {
        for (int i = threadIdx.x; i < PAIR_FLOATS; i += 256)
            sg[i] = __float_as_uint(myrep[i]);     // values are >= 0
    } else {
        for (int i = threadIdx.x; i < PAIR_FLOATS; i += 256)
            sg[i] = 0u;
    }
    __syncthreads();

    int chunk = (m + K - 1) / K;
    int start = rep * chunk;
    int end   = min(m, start + chunk);
    const float4* v = vals  + (size_t)pair * m;
    const int*    c = cells + (size_t)pair * m;

    for (int i = start + (int)threadIdx.x; i < end; i += 256) {
        float4 o = v[i];
        int cell = c[i];
        if (o.x > 0.0f) atomicMax(&sg[          cell], __float_as_uint(o.x));
        if (o.y > 0.0f) atomicMax(&sg[    G3 + cell], __float_as_uint(o.y));
        if (o.z > 0.0f) atomicMax(&sg[2 * G3 + cell], __float_as_uint(o.z));
        if (o.w > 0.0f) atomicMax(&sg[3 * G3 + cell], __float_as_uint(o.w));
    }
    __syncthreads();

    for (int i = threadIdx.x; i < PAIR_FLOATS; i += 256)
        myrep[i] = __uint_as_float(sg[i]);
}

// ---------------------------------------------------------------------------
// max-reduce K replicas per pair -> scenes [B,12,G3] (== [pair][13500] linear)
// ---------------------------------------------------------------------------
__global__ __launch_bounds__(256)
void reduce_kernel(const float* __restrict__ scenesR, float* __restrict__ scenes,
                   int K)
{
    int t = blockIdx.x * 256 + threadIdx.x;
    if (t >= SCENE_FLOATS) return;
    int pair = t / PAIR_FLOATS;
    int j    = t - pair * PAIR_FLOATS;
    const float* src = scenesR + (size_t)pair * K * PAIR_FLOATS + j;
    float mx = 0.0f;
    for (int r = 0; r < K; ++r)
        mx = fmaxf(mx, src[(size_t)r * PAIR_FLOATS]);
    scenes[t] = mx;
}

// ---------------------------------------------------------------------------
// conv1: scenes [B,12,15,15,15] -> y0 [B,8,8,8,8] (raw conv+bias) + stats0
// ---------------------------------------------------------------------------
__global__ __launch_bounds__(256)
void conv1_kernel(const float* __restrict__ scenes,
                  const float* __restrict__ w,    // [8,12,125]
                  const float* __restrict__ bias, // [8]
                  float* __restrict__ y, float* __restrict__ stats)
{
    __shared__ float sred[256];
    int bx = blockIdx.x;
    int od = bx & 7, co = (bx >> 3) & 7, b = bx >> 6;
    int tid = threadIdx.x;
    int ow = tid & 7, oh = (tid >> 3) & 7, ciq = tid >> 6;

    float s = 0.0f;
    for (int cin = 0; cin < 3; ++cin) {
        int ci = ciq * 3 + cin;
        const float* sc = scenes + (size_t)(b * 12 + ci) * G3;
        const float* wc = w + (size_t)(co * 12 + ci) * 125;
#pragma unroll
        for (int kd = 0; kd < 5; ++kd) {
            int id = od * 2 - 2 + kd;
            if ((unsigned)id >= (unsigned)G) continue;   // block-uniform
#pragma unroll
            for (int kh = 0; kh < 5; ++kh) {
                int ih = oh * 2 - 2 + kh;
                bool hok = (unsigned)ih < (unsigned)G;
#pragma unroll
                for (int kw = 0; kw < 5; ++kw) {
                    int iw = ow * 2 - 2 + kw;
                    if (hok && (unsigned)iw < (unsigned)G)
                        s = fmaf(sc[(id * G + ih) * G + iw], wc[kd*25 + kh*5 + kw], s);
                }
            }
        }
    }
    sred[tid] = s;
    __syncthreads();
    if (tid < 64) {
        float tot = sred[tid] + sred[64+tid] + sred[128+tid] + sred[192+tid] + bias[co];
        y[(size_t)(b * 8 + co) * 512 + od * 64 + tid] = tot;
        float sum = tot, sq = tot * tot;
#pragma unroll
        for (int o = 32; o > 0; o >>= 1) {
            sum += __shfl_down(sum, o, 64);
            sq  += __shfl_down(sq,  o, 64);
        }
        if (tid == 0) { atomicAdd(&stats[co], sum); atomicAdd(&stats[8 + co], sq); }
    }
}

// ---------------------------------------------------------------------------
// conv_s: BN(stats_in,g,beta)+ELU applied to yin on the fly, then 5^3 conv
// ---------------------------------------------------------------------------
__global__ __launch_bounds__(256)
void conv_s_kernel(const float* __restrict__ yin,
                   const float* __restrict__ w,     // [8,8,125] this layer
                   const float* __restrict__ bias,  // [8]
                   const float* __restrict__ g, const float* __restrict__ bet,
                   const float* __restrict__ stats_in,
                   float* __restrict__ yout, float* __restrict__ stats_out)
{
    __shared__ float slab[8 * 5 * 144];   // [ci][kd][12][12], zero-padded
    __shared__ float sscale[8], sshift[8];
    __shared__ float sred[256];

    int bx = blockIdx.x;
    int od = bx & 7, co = (bx >> 3) & 7, b = bx >> 6;
    int tid = threadIdx.x;

    if (tid < 8) {
        float S = stats_in[tid], Q = stats_in[8 + tid];
        float m  = S * (1.0f / 2048.0f);
        float vv = Q * (1.0f / 2048.0f) - m * m;
        float rs = rsqrtf(vv + 1e-5f);
        float sc = g[tid] * rs;
        sscale[tid] = sc;
        sshift[tid] = bet[tid] - m * sc;
    }
    __syncthreads();

    for (int s = tid; s < 5760; s += 256) {
        int ci = s / 720; int r = s % 720;
        int kd = r / 144; int r2 = r % 144;
        int ph = r2 / 12, pw = r2 % 12;
        int id = od - 2 + kd, ih = ph - 2, iw = pw - 2;
        float v = 0.0f;
        if ((unsigned)id < 8u && (unsigned)ih < 8u && (unsigned)iw < 8u) {
            float raw = yin[(size_t)(b * 8 + ci) * 512 + id * 64 + ih * 8 + iw];
            float t = fmaf(raw, sscale[ci], sshift[ci]);
            v = t > 0.0f ? t : __expf(t) - 1.0f;
        }
        slab[s] = v;
    }
    __syncthreads();

    int ow = tid & 7, oh = (tid >> 3) & 7, ciq = tid >> 6;
    float s = 0.0f;
#pragma unroll
    for (int c2 = 0; c2 < 2; ++c2) {
        int ci = ciq * 2 + c2;
        const float* sl = slab + ci * 720;
        const float* wc = w + (size_t)(co * 8 + ci) * 125;
#pragma unroll
        for (int kd = 0; kd < 5; ++kd) {
#pragma unroll
            for (int kh = 0; kh < 5; ++kh) {
                const float* row = sl + kd * 144 + (oh + kh) * 12 + ow;
                const float* wr = wc + kd * 25 + kh * 5;
#pragma unroll
                for (int kw = 0; kw < 5; ++kw) s = fmaf(row[kw], wr[kw], s);
            }
        }
    }
    sred[tid] = s;
    __syncthreads();
    if (tid < 64) {
        float tot = sred[tid] + sred[64+tid] + sred[128+tid] + sred[192+tid] + bias[co];
        yout[(size_t)(b * 8 + co) * 512 + od * 64 + tid] = tot;
        float sum = tot, sq = tot * tot;
#pragma unroll
        for (int o = 32; o > 0; o >>= 1) {
            sum += __shfl_down(sum, o, 64);
            sq  += __shfl_down(sq,  o, 64);
        }
        if (tid == 0) { atomicAdd(&stats_out[co], sum); atomicAdd(&stats_out[8 + co], sq); }
    }
}

// ---------------------------------------------------------------------------
// final BN + ELU -> d_out
// ---------------------------------------------------------------------------
__global__ __launch_bounds__(256)
void bn_final_kernel(const float* __restrict__ yin,
                     const float* __restrict__ g, const float* __restrict__ bet,
                     const float* __restrict__ stats_in, float* __restrict__ outp)
{
    int i = blockIdx.x * 256 + threadIdx.x;   // 16384 total
    int c = (i >> 9) & 7;
    float S = stats_in[c], Q = stats_in[8 + c];
    float m  = S * (1.0f / 2048.0f);
    float vv = Q * (1.0f / 2048.0f) - m * m;
    float rs = rsqrtf(vv + 1e-5f);
    float sc = g[c] * rs;
    float sh = bet[c] - m * sc;
    float t = fmaf(yin[i], sc, sh);
    outp[i] = t > 0.0f ? t : __expf(t) - 1.0f;
}

// ---------------------------------------------------------------------------
extern "C" void kernel_launch(void* const* d_in, const int* in_sizes, int n_in,
                              void* d_out, int out_size, void* d_ws, size_t ws_size,
                              hipStream_t stream)
{
    const float* goals       = (const float*)d_in[0];
    const float* inputs      = (const float*)d_in[1];
    const float* backgrounds = (const float*)d_in[2];
    const float* W1 = (const float*)d_in[3];
    const float* b1 = (const float*)d_in[4];
    const float* W2 = (const float*)d_in[5];
    const float* b2 = (const float*)d_in[6];
    const float* W3 = (const float*)d_in[7];
    const float* b3 = (const float*)d_in[8];
    const float* conv1_w = (const float*)d_in[9];
    const float* conv1_b = (const float*)d_in[10];
    const float* bn1_g   = (const float*)d_in[11];
    const float* bn1_b   = (const float*)d_in[12];
    const float* convs_w = (const float*)d_in[13];
    const float* convs_b = (const float*)d_in[14];
    const float* bns_g   = (const float*)d_in[15];
    const float* bns_b   = (const float*)d_in[16];

    // --- pick (K replicas, S segments) to fit the workspace -----------------
    // floats needed: 48*Mseg (vals) + 12*Mseg (cells) + K*SCENE + SCENE + 2*16384 + 112
    long ws_floats = (long)(ws_size / 4);
    long fixed = SCENE_FLOATS + 2L * 16384 + 112;
    static const int plans[][2] = {
        {42,1},{42,2},{42,4},{24,4},{21,6},{16,8},{8,12},{4,16},{2,32},{1,64}};
    int K = 1, S = 64;
    for (int pi = 0; pi < 10; ++pi) {
        int pk = plans[pi][0], ps = plans[pi][1];
        long mseg = (NPTS + ps - 1) / ps;
        long need = 60L * mseg + (long)pk * SCENE_FLOATS + fixed;
        if (need <= ws_floats) { K = pk; S = ps; break; }
    }
    int Mseg = (NPTS + S - 1) / S;

    float*  wsp     = (float*)d_ws;
    float4* vals    = (float4*)wsp;                          // 12*Mseg float4
    int*    cells   = (int*)(wsp + 48L * Mseg);              // 12*Mseg ints
    float*  scenesR = wsp + 60L * Mseg;                      // K * SCENE_FLOATS
    float*  scenes  = scenesR + (size_t)K * SCENE_FLOATS;    // 162000
    float*  yA      = scenes + SCENE_FLOATS;                 // 16384
    float*  yB      = yA + 16384;                            // 16384
    float*  stats   = yB + 16384;                            // 7*16 floats

    hipMemsetAsync(stats, 0, 7 * 16 * sizeof(float), stream);

    for (int s = 0; s < S; ++s) {
        int s0 = s * Mseg;
        int m  = min(Mseg, NPTS - s0);
        dim3 agrid((m + 255) / 256, B, 3);
        mlp_kernel<<<agrid, 256, 0, stream>>>(inputs, goals, backgrounds,
                                              W1, b1, W2, b2, W3, b3,
                                              vals, cells, s0, m);
        dim3 bgrid(K, B, 3);
        scatter_kernel<<<bgrid, 256, 0, stream>>>(vals, cells, scenesR, K, m,
                                                  s > 0 ? 1 : 0);
    }

    reduce_kernel<<<(SCENE_FLOATS + 255) / 256, 256, 0, stream>>>(scenesR, scenes, K);

    conv1_kernel<<<256, 256, 0, stream>>>(scenes, conv1_w, conv1_b, yA, stats);

    const float* cur = yA;
    float* nxt = yB;
    for (int i = 0; i < 6; ++i) {
        const float* g   = (i == 0) ? bn1_g : (bns_g + (i - 1) * 8);
        const float* bet = (i == 0) ? bn1_b : (bns_b + (i - 1) * 8);
        conv_s_kernel<<<256, 256, 0, stream>>>(
            cur, convs_w + (size_t)i * 8000, convs_b + i * 8,
            g, bet, stats + i * 16, nxt, stats + (i + 1) * 16);
        const float* tmp = cur; cur = nxt; nxt = (float*)tmp;
    }

    bn_final_kernel<<<64, 256, 0, stream>>>(cur, bns_g + 5 * 8, bns_b + 5 * 8,
                                            stats + 6 * 16, (float*)d_out);
}